// Round 4
// baseline (366.256 us; speedup 1.0000x reference)
//
#include <hip/hip_runtime.h>
#include <math.h>

#define IN_DIM 512
#define MID 32
#define OUT_DIM 512
#define BATCH 32
#define HW 4096  // 64*64

typedef float vfloat4 __attribute__((ext_vector_type(4)));
typedef const __attribute__((address_space(1))) unsigned int* gas_ptr;
typedef __attribute__((address_space(3))) unsigned int* las_ptr;

// One WAVE per (b,c) plane. Plane (16 KB) is DMA'd global->LDS with
// global_load_lds (width=16): no data VGPRs consumed, so 16 x 1 KB DMAs
// per wave stay in flight (128 KB/CU with 2 resident blocks) -> HBM saturated.
// Then each wave reduces its own 16 KB LDS region.
__global__ __launch_bounds__(256) void pool_kernel(const float* __restrict__ x,
                                                   float* __restrict__ pooled) {
    __shared__ float lds[4][HW];  // 64 KB: 16 KB per wave -> 2 blocks/CU
    const int wave = threadIdx.x >> 6;
    const int lane = threadIdx.x & 63;
    const int plane = blockIdx.x * 4 + wave;  // 0 .. B*C-1
    const float* gp = x + (size_t)plane * HW;
    float* lp = &lds[wave][0];

    // 16 DMA instructions, each moves 1 KB (64 lanes x 16 B), identity layout:
    // LDS dest = wave-uniform base + lane*16 (matches gp + i*1024 + lane*16).
#pragma unroll
    for (int i = 0; i < 16; ++i) {
        __builtin_amdgcn_global_load_lds((gas_ptr)(gp + i * 256 + lane * 4),
                                         (las_ptr)(lp + i * 256), 16, 0, 0);
    }
    // __syncthreads drains vmcnt(0) (DMA completion) before the barrier.
    __syncthreads();

    const vfloat4* lv = (const vfloat4*)lp;
    float s0 = 0.f, s1 = 0.f, s2 = 0.f, s3 = 0.f;
#pragma unroll
    for (int i = 0; i < 4; ++i) {
        vfloat4 v0 = lv[lane + 64 * (4 * i + 0)];
        vfloat4 v1 = lv[lane + 64 * (4 * i + 1)];
        vfloat4 v2 = lv[lane + 64 * (4 * i + 2)];
        vfloat4 v3 = lv[lane + 64 * (4 * i + 3)];
        s0 += (v0.x + v0.y) + (v0.z + v0.w);
        s1 += (v1.x + v1.y) + (v1.z + v1.w);
        s2 += (v2.x + v2.y) + (v2.z + v2.w);
        s3 += (v3.x + v3.y) + (v3.z + v3.w);
    }
    float s = (s0 + s1) + (s2 + s3);

    // 64-lane butterfly reduce
#pragma unroll
    for (int off = 32; off > 0; off >>= 1) s += __shfl_down(s, off, 64);

    if (lane == 0) pooled[plane] = s * (1.0f / (float)HW);
}

// One block per batch row. Bottleneck (512->32, ReLU) then expansion (32->512, sigmoid).
__global__ __launch_bounds__(256) void mlp_kernel(const float* __restrict__ pooled,
                                                  const float* __restrict__ w1,
                                                  const float* __restrict__ b1,
                                                  const float* __restrict__ w2,
                                                  const float* __restrict__ b2,
                                                  float* __restrict__ out) {
    const int b = blockIdx.x;  // 0..31
    const int tid = threadIdx.x;

    __shared__ float sp[IN_DIM];
    __shared__ float sh[MID];

    sp[tid] = pooled[b * IN_DIM + tid];
    sp[tid + 256] = pooled[b * IN_DIM + tid + 256];
    __syncthreads();

    if (tid < MID) {
        float acc = b1[tid];
        const float4* wr = (const float4*)(w1 + tid * IN_DIM);
        const float4* spv = (const float4*)sp;
#pragma unroll 4
        for (int c = 0; c < IN_DIM / 4; ++c) {
            float4 w = wr[c];
            float4 p = spv[c];
            acc += w.x * p.x + w.y * p.y + w.z * p.z + w.w * p.w;
        }
        sh[tid] = fmaxf(acc, 0.f);
    }
    __syncthreads();

#pragma unroll
    for (int r = 0; r < 2; ++r) {
        const int o = tid + r * 256;
        float acc = b2[o];
        const float* wr = w2 + o * MID;
#pragma unroll
        for (int m = 0; m < MID; ++m) acc += sh[m] * wr[m];
        out[b * OUT_DIM + o] = 1.0f / (1.0f + expf(-acc));
    }
}

extern "C" void kernel_launch(void* const* d_in, const int* in_sizes, int n_in,
                              void* d_out, int out_size, void* d_ws, size_t ws_size,
                              hipStream_t stream) {
    const float* x  = (const float*)d_in[0];
    const float* w1 = (const float*)d_in[1];
    const float* b1 = (const float*)d_in[2];
    const float* w2 = (const float*)d_in[3];
    const float* b2 = (const float*)d_in[4];
    float* out = (float*)d_out;
    float* pooled = (float*)d_ws;  // BATCH*IN_DIM floats = 64 KiB

    pool_kernel<<<(BATCH * IN_DIM) / 4, 256, 0, stream>>>(x, pooled);
    mlp_kernel<<<BATCH, 256, 0, stream>>>(pooled, w1, b1, w2, b2, out);
}

// Round 5
// 350.125 us; speedup vs baseline: 1.0461x; 1.0461x over previous
//
#include <hip/hip_runtime.h>
#include <math.h>

#define IN_DIM 512
#define MID 32
#define OUT_DIM 512
#define BATCH 32
#define HW 4096  // 64*64

typedef float vfloat4 __attribute__((ext_vector_type(4)));

// One WAVE per (b,c) plane: 4096 contiguous floats = 64 lanes x 16 float4.
// No LDS, no __syncthreads. All 16 nontemporal loads are issued into
// registers BEFORE any reduction math, so the full 256 B/lane is in flight
// under one vmcnt window (max memory-level parallelism per wave).
__global__ __launch_bounds__(256) void pool_kernel(const float* __restrict__ x,
                                                   float* __restrict__ pooled) {
    const int wave = threadIdx.x >> 6;
    const int lane = threadIdx.x & 63;
    const int plane = blockIdx.x * 4 + wave;  // 0 .. B*C-1
    const vfloat4* xp = (const vfloat4*)(x + (size_t)plane * HW);

    vfloat4 v[16];
#pragma unroll
    for (int i = 0; i < 16; ++i)
        v[i] = __builtin_nontemporal_load(&xp[lane + 64 * i]);

    float s0 = 0.f, s1 = 0.f, s2 = 0.f, s3 = 0.f;
#pragma unroll
    for (int i = 0; i < 4; ++i) {
        s0 += (v[4 * i + 0].x + v[4 * i + 0].y) + (v[4 * i + 0].z + v[4 * i + 0].w);
        s1 += (v[4 * i + 1].x + v[4 * i + 1].y) + (v[4 * i + 1].z + v[4 * i + 1].w);
        s2 += (v[4 * i + 2].x + v[4 * i + 2].y) + (v[4 * i + 2].z + v[4 * i + 2].w);
        s3 += (v[4 * i + 3].x + v[4 * i + 3].y) + (v[4 * i + 3].z + v[4 * i + 3].w);
    }
    float s = (s0 + s1) + (s2 + s3);

    // 64-lane butterfly reduce
#pragma unroll
    for (int off = 32; off > 0; off >>= 1) s += __shfl_down(s, off, 64);

    if (lane == 0) pooled[plane] = s * (1.0f / (float)HW);
}

// One block per batch row. Bottleneck (512->32, ReLU) then expansion (32->512, sigmoid).
__global__ __launch_bounds__(256) void mlp_kernel(const float* __restrict__ pooled,
                                                  const float* __restrict__ w1,
                                                  const float* __restrict__ b1,
                                                  const float* __restrict__ w2,
                                                  const float* __restrict__ b2,
                                                  float* __restrict__ out) {
    const int b = blockIdx.x;  // 0..31
    const int tid = threadIdx.x;

    __shared__ float sp[IN_DIM];
    __shared__ float sh[MID];

    sp[tid] = pooled[b * IN_DIM + tid];
    sp[tid + 256] = pooled[b * IN_DIM + tid + 256];
    __syncthreads();

    if (tid < MID) {
        float acc = b1[tid];
        const float4* wr = (const float4*)(w1 + tid * IN_DIM);
        const float4* spv = (const float4*)sp;
#pragma unroll 4
        for (int c = 0; c < IN_DIM / 4; ++c) {
            float4 w = wr[c];
            float4 p = spv[c];
            acc += w.x * p.x + w.y * p.y + w.z * p.z + w.w * p.w;
        }
        sh[tid] = fmaxf(acc, 0.f);
    }
    __syncthreads();

#pragma unroll
    for (int r = 0; r < 2; ++r) {
        const int o = tid + r * 256;
        float acc = b2[o];
        const float* wr = w2 + o * MID;
#pragma unroll
        for (int m = 0; m < MID; ++m) acc += sh[m] * wr[m];
        out[b * OUT_DIM + o] = 1.0f / (1.0f + expf(-acc));
    }
}

extern "C" void kernel_launch(void* const* d_in, const int* in_sizes, int n_in,
                              void* d_out, int out_size, void* d_ws, size_t ws_size,
                              hipStream_t stream) {
    const float* x  = (const float*)d_in[0];
    const float* w1 = (const float*)d_in[1];
    const float* b1 = (const float*)d_in[2];
    const float* w2 = (const float*)d_in[3];
    const float* b2 = (const float*)d_in[4];
    float* out = (float*)d_out;
    float* pooled = (float*)d_ws;  // BATCH*IN_DIM floats = 64 KiB

    pool_kernel<<<(BATCH * IN_DIM) / 4, 256, 0, stream>>>(x, pooled);
    mlp_kernel<<<BATCH, 256, 0, stream>>>(pooled, w1, b1, w2, b2, out);
}